// Round 1
// baseline (644.196 us; speedup 1.0000x reference)
//
#include <hip/hip_runtime.h>
#include <cstdint>
#include <cstddef>

#define NE 1024   // embedding dim
#define HS 64     // head size
#define TT 2048   // sequence length
#define BB 8      // batch

// ---------------------------------------------------------------------------
// Kernel 1: projections  q = x@Wq^T, k = x@Wk^T, v = (x@Wv^T) * HS^-0.5
// grid = (B*T)/16 = 1024 blocks, 256 threads.
// Each block: 16 rows of x staged in LDS (64 KB), each thread computes
// 4 rows x 1 col for all three weight matrices (12 accumulators).
// W rows are read from global (768 KB total -> L2-resident).
// ---------------------------------------------------------------------------
__global__ __launch_bounds__(256) void proj_kernel(
    const float* __restrict__ x,
    const float* __restrict__ Wq, const float* __restrict__ Wk,
    const float* __restrict__ Wv,
    float* __restrict__ q, float* __restrict__ k, float* __restrict__ v)
{
    __shared__ float xs[16 * NE];                 // 64 KB
    const int row0 = blockIdx.x * 16;

    // cooperative load: 16 rows x 1024 f32 = 4096 float4 (contiguous)
    const float4* xsrc = reinterpret_cast<const float4*>(x + (size_t)row0 * NE);
    float4* xdst = reinterpret_cast<float4*>(xs);
#pragma unroll
    for (int i = 0; i < 16; ++i)
        xdst[threadIdx.x + 256 * i] = xsrc[threadIdx.x + 256 * i];
    __syncthreads();

    const int c    = threadIdx.x & 63;            // output column 0..63
    const int half = threadIdx.x >> 6;            // 0..3 -> rows half*4..+3

    float qa[4] = {0.f, 0.f, 0.f, 0.f};
    float ka[4] = {0.f, 0.f, 0.f, 0.f};
    float va[4] = {0.f, 0.f, 0.f, 0.f};

    const float4* wq4 = reinterpret_cast<const float4*>(Wq + (size_t)c * NE);
    const float4* wk4 = reinterpret_cast<const float4*>(Wk + (size_t)c * NE);
    const float4* wv4 = reinterpret_cast<const float4*>(Wv + (size_t)c * NE);

    for (int e4 = 0; e4 < NE / 4; ++e4) {
        const float4 wq = wq4[e4];
        const float4 wk = wk4[e4];
        const float4 wv = wv4[e4];
#pragma unroll
        for (int i = 0; i < 4; ++i) {
            const float4 xv =
                *reinterpret_cast<const float4*>(&xs[(half * 4 + i) * NE + e4 * 4]);
            qa[i] += xv.x * wq.x + xv.y * wq.y + xv.z * wq.z + xv.w * wq.w;
            ka[i] += xv.x * wk.x + xv.y * wk.y + xv.z * wk.z + xv.w * wk.w;
            va[i] += xv.x * wv.x + xv.y * wv.y + xv.z * wv.z + xv.w * wv.w;
        }
    }

#pragma unroll
    for (int i = 0; i < 4; ++i) {
        const size_t r = (size_t)row0 + half * 4 + i;
        q[r * HS + c] = qa[i];
        k[r * HS + c] = ka[i];
        v[r * HS + c] = va[i] * 0.125f;           // HEAD_SIZE^-0.5
    }
}

// ---------------------------------------------------------------------------
// Kernel 2: causal attention for a 16-row query tile of one batch.
// grid = B * (T/16) = 1024 blocks, 512 threads.
// Phase 1 (QK^T): threads laid out as (c = tid&31, r = tid>>5); thread owns
//   row r, k-columns {c + 32j}. q-row held in 16 float4 VGPRs; k tiles (64
//   rows, stride 68 f32 -> conflict-free b128) staged in LDS. Scores go to a
//   16x2048 LDS buffer (128 KB).
// Phase 2 (softmax): per-row max/sum via width-32 shfl_xor (a row is 32
//   consecutive lanes). Normalized A written to global + back into s_lds.
// Phase 3 (A@V): threads re-laid as (h = tid&63, rr = tid>>6); v tiles staged
//   in the same LDS buffer; A read broadcast from s_lds.
// ---------------------------------------------------------------------------
__global__ __launch_bounds__(512) void attn_kernel(
    const float* __restrict__ q, const float* __restrict__ kmat,
    const float* __restrict__ vmat,
    float* __restrict__ A, float* __restrict__ out)
{
    __shared__ float s_lds[16 * TT];              // 128 KB score tile
    __shared__ float kv[64 * 68];                 // 17.4 KB k/v staging

    const int bid = blockIdx.x;
    const int b   = bid & 7;
    const int qt  = 127 - (bid >> 3);             // longest tiles first
    const int Q0  = qt * 16;

    const int tid = threadIdx.x;
    const int c   = tid & 31;                     // k-column group
    const int r   = tid >> 5;                     // query row 0..15
    const int grow = Q0 + r;                      // row within batch
    const size_t base = (size_t)b * TT * HS;

    // q row -> registers (16 float4 = 64 VGPR)
    float4 qreg[16];
    {
        const float4* qrow =
            reinterpret_cast<const float4*>(q + base + (size_t)grow * HS);
#pragma unroll
        for (int i = 0; i < 16; ++i) qreg[i] = qrow[i];
    }

    const int ntiles = (Q0 + 15) / 64 + 1;        // 64-row k tiles needed

    // ---------------- Phase 1: QK^T ----------------
    for (int t = 0; t < ntiles; ++t) {
        __syncthreads();                          // protect kv reuse
        {
            const float4* src = reinterpret_cast<const float4*>(
                kmat + base + (size_t)t * 64 * HS);
#pragma unroll
            for (int i = 0; i < 2; ++i) {
                const int idx = tid + 512 * i;    // 1024 float4 total
                const int rw = idx >> 4, cc = idx & 15;
                *reinterpret_cast<float4*>(&kv[rw * 68 + cc * 4]) = src[idx];
            }
        }
        __syncthreads();
#pragma unroll
        for (int jj = 0; jj < 2; ++jj) {
            const int kr = c + 32 * jj;           // local row in tile
            const int kg = t * 64 + kr;           // global k index
            float acc = 0.f;
#pragma unroll
            for (int e4 = 0; e4 < 16; ++e4) {
                const float4 k4 =
                    *reinterpret_cast<const float4*>(&kv[kr * 68 + e4 * 4]);
                const float4 q4 = qreg[e4];
                acc += q4.x * k4.x + q4.y * k4.y + q4.z * k4.z + q4.w * k4.w;
            }
            if (kg > grow) acc = -1e30f;          // causal mask
            s_lds[r * TT + kg] = acc;
        }
    }
    // fill untouched columns (k >= ntiles*64) with mask sentinel
    for (int kg = ntiles * 64 + c; kg < TT; kg += 32)
        s_lds[r * TT + kg] = -1e30f;

    // ---------------- Phase 2: softmax ----------------
    float m = -1e30f;
#pragma unroll
    for (int j = 0; j < 64; ++j)
        m = fmaxf(m, s_lds[r * TT + c + 32 * j]);
#pragma unroll
    for (int mask = 16; mask > 0; mask >>= 1)
        m = fmaxf(m, __shfl_xor(m, mask, 32));

    float sum = 0.f;
#pragma unroll
    for (int j = 0; j < 64; ++j) {
        const int kg = c + 32 * j;
        const float e = __expf(s_lds[r * TT + kg] - m);
        s_lds[r * TT + kg] = e;
        sum += e;
    }
#pragma unroll
    for (int mask = 16; mask > 0; mask >>= 1)
        sum += __shfl_xor(sum, mask, 32);
    const float inv = 1.f / sum;

    float* Arow = A + ((size_t)b * TT + grow) * TT;
#pragma unroll
    for (int j = 0; j < 64; ++j) {
        const int kg = c + 32 * j;
        const float a = s_lds[r * TT + kg] * inv;
        s_lds[r * TT + kg] = a;                   // normalized A for phase 3
        Arow[kg] = a;                             // coalesced 128B segments
    }

    // ---------------- Phase 3: out = A @ v ----------------
    const int hh = tid & 63;                      // head dim (lane id)
    const int rr = tid >> 6;                      // 0..7 -> rows rr, rr+8
    float o1 = 0.f, o2 = 0.f;

    for (int t = 0; t < ntiles; ++t) {
        __syncthreads();                          // s_lds writes + kv reuse
        {
            const float4* src = reinterpret_cast<const float4*>(
                vmat + base + (size_t)t * 64 * HS);
#pragma unroll
            for (int i = 0; i < 2; ++i) {
                const int idx = tid + 512 * i;
                const int rw = idx >> 4, cc = idx & 15;
                *reinterpret_cast<float4*>(&kv[rw * 68 + cc * 4]) = src[idx];
            }
        }
        __syncthreads();
#pragma unroll
        for (int kk4 = 0; kk4 < 16; ++kk4) {
            const float4 a1 = *reinterpret_cast<const float4*>(
                &s_lds[(size_t)rr * TT + t * 64 + kk4 * 4]);
            const float4 a2 = *reinterpret_cast<const float4*>(
                &s_lds[(size_t)(rr + 8) * TT + t * 64 + kk4 * 4]);
            const float* a1p = reinterpret_cast<const float*>(&a1);
            const float* a2p = reinterpret_cast<const float*>(&a2);
#pragma unroll
            for (int u = 0; u < 4; ++u) {
                const float vval = kv[(kk4 * 4 + u) * 68 + hh];
                o1 += a1p[u] * vval;
                o2 += a2p[u] * vval;
            }
        }
    }

    out[((size_t)b * TT + Q0 + rr) * HS + hh]     = o1;
    out[((size_t)b * TT + Q0 + rr + 8) * HS + hh] = o2;
}

// ---------------------------------------------------------------------------
extern "C" void kernel_launch(void* const* d_in, const int* in_sizes, int n_in,
                              void* d_out, int out_size, void* d_ws,
                              size_t ws_size, hipStream_t stream)
{
    (void)in_sizes; (void)n_in; (void)out_size; (void)ws_size;

    // setup_inputs() dict order: x, Wk, Wq, Wv
    const float* x  = (const float*)d_in[0];
    const float* Wk = (const float*)d_in[1];
    const float* Wq = (const float*)d_in[2];
    const float* Wv = (const float*)d_in[3];

    float* A   = (float*)d_out;                         // (B,T,T)
    float* out = A + (size_t)BB * TT * TT;              // (B,T,H)

    // workspace: q,k,v fp32 = 3 * 4 MB (ws assumed >= 12 MB)
    float* qd = (float*)d_ws;
    float* kd = qd + (size_t)BB * TT * HS;
    float* vd = kd + (size_t)BB * TT * HS;

    proj_kernel<<<(BB * TT) / 16, 256, 0, stream>>>(x, Wq, Wk, Wv, qd, kd, vd);
    attn_kernel<<<BB * (TT / 16), 512, 0, stream>>>(qd, kd, vd, A, out);
}

// Round 2
// 282.735 us; speedup vs baseline: 2.2784x; 2.2784x over previous
//
#include <hip/hip_runtime.h>
#include <cstdint>
#include <cstddef>

#define NE 1024   // embedding dim
#define HS 64     // head size
#define TT 2048   // sequence length
#define BB 8      // batch

typedef short bf16x8 __attribute__((ext_vector_type(8)));
typedef float f32x4  __attribute__((ext_vector_type(4)));

// round-to-nearest-even f32 -> bf16 (bit pattern as ushort)
__device__ __forceinline__ unsigned short f2b(float f) {
    union { float f; uint32_t u; } v; v.f = f;
    uint32_t r = v.u + 0x7fffu + ((v.u >> 16) & 1u);
    return (unsigned short)(r >> 16);
}
__device__ __forceinline__ float b2f(unsigned short b) {
    union { uint32_t u; float f; } v; v.u = ((uint32_t)b) << 16;
    return v.f;
}

// ---------------------------------------------------------------------------
// Kernel 0: convert W = [Wq;Wk;Wv*0.125] (192 x 1024 f32) into MFMA B-fragment
// order, split hi/lo bf16.  Fragment layout for mfma_f32_16x16x32_bf16:
// lane L holds B[k = kc*32 + (L>>4)*8 + j][col = ntile*16 + (L&15)], j=0..7.
// Storage: frag_idx = (ntg*32 + kcg)*64 + L, 8 bf16 (16 B) contiguous.
// 24576 fragments total = 384 KB per array (hi, lo) -> L2-resident.
// ---------------------------------------------------------------------------
__global__ __launch_bounds__(256) void wprep_kernel(
    const float* __restrict__ Wq, const float* __restrict__ Wk,
    const float* __restrict__ Wv,
    unsigned short* __restrict__ whf, unsigned short* __restrict__ wlf)
{
    const int t   = blockIdx.x * 256 + threadIdx.x;   // 0..24575
    const int L   = t & 63;
    const int kcg = (t >> 6) & 31;
    const int ntg = t >> 11;                          // 0..11
    const int col = ntg * 16 + (L & 15);              // 0..191
    const int k0  = kcg * 32 + (L >> 4) * 8;

    const float* W;
    float scale = 1.f;
    if (col < 64)        W = Wq + (size_t)col * NE;
    else if (col < 128)  W = Wk + (size_t)(col - 64) * NE;
    else               { W = Wv + (size_t)(col - 128) * NE; scale = 0.125f; }

    bf16x8 h, l;
#pragma unroll
    for (int j = 0; j < 8; ++j) {
        const float f = W[k0 + j] * scale;
        const unsigned short hb = f2b(f);
        const unsigned short lb = f2b(f - b2f(hb));
        h[j] = (short)hb;
        l[j] = (short)lb;
    }
    *reinterpret_cast<bf16x8*>(whf + (size_t)t * 8) = h;
    *reinterpret_cast<bf16x8*>(wlf + (size_t)t * 8) = l;
}

// ---------------------------------------------------------------------------
// Kernel 1: projections via split-bf16 MFMA.
// C[16384 x 192] = x[16384 x 1024] @ W^T, computed as
//   xh@wh + xh@wl + xl@wh   (error ~2^-17 relative).
// Grid 256 blocks (BM=64), 256 threads = 4 waves; wave w owns cols
// [w*48, w*48+48) (3 n-tiles), all 64 rows (4 m-tiles).
// x tile (64x64) reg-staged, converted hi/lo, stored XOR-swizzled in LDS
// (byte ^= (row&7)<<4) -> conflict-free ds_read_b128 / ds_write_b128.
// B-fragments loaded straight from the pre-arranged whf/wlf (L2).
// ---------------------------------------------------------------------------
__global__ __launch_bounds__(256) void proj_mfma(
    const float* __restrict__ x,
    const unsigned short* __restrict__ whf,
    const unsigned short* __restrict__ wlf,
    float* __restrict__ q, float* __restrict__ k, float* __restrict__ v)
{
    __shared__ unsigned short xh[64 * 64];   // 8 KB, swizzled
    __shared__ unsigned short xl[64 * 64];   // 8 KB, swizzled

    const int tid  = threadIdx.x;
    const int L    = tid & 63;
    const int w    = tid >> 6;               // wave id 0..3
    const int row0 = blockIdx.x * 64;

    f32x4 acc[4][3] = {};                    // [m-tile][n-tile]

    // staging geometry: thread covers row srow, element cols [sk0, sk0+16)
    const int srow = tid >> 2;               // 0..63
    const int sk0  = (tid & 3) * 16;
    const float* xsrc = x + (size_t)(row0 + srow) * NE + sk0;

    for (int ks = 0; ks < 16; ++ks) {        // K loop, BK = 64
        __syncthreads();                     // protect previous-step reads
        {
            const float4* s4 = reinterpret_cast<const float4*>(xsrc + ks * 64);
            float xv[16];
#pragma unroll
            for (int i = 0; i < 4; ++i) {
                const float4 f = s4[i];
                xv[4*i+0] = f.x; xv[4*i+1] = f.y; xv[4*i+2] = f.z; xv[4*i+3] = f.w;
            }
#pragma unroll
            for (int c = 0; c < 2; ++c) {    // two 16B chunks (8 elems each)
                bf16x8 hv, lv;
#pragma unroll
                for (int j = 0; j < 8; ++j) {
                    const float f = xv[c * 8 + j];
                    const unsigned short hb = f2b(f);
                    const unsigned short lb = f2b(f - b2f(hb));
                    hv[j] = (short)hb;
                    lv[j] = (short)lb;
                }
                const int kb16 = (tid & 3) * 2 + c;               // 16B col idx
                const int off  = srow * 64 + ((kb16 ^ (srow & 7)) << 3);
                *reinterpret_cast<bf16x8*>(&xh[off]) = hv;
                *reinterpret_cast<bf16x8*>(&xl[off]) = lv;
            }
        }
        __syncthreads();

#pragma unroll
        for (int kc = 0; kc < 2; ++kc) {     // two K=32 chunks per step
            bf16x8 ah[4], al[4];
#pragma unroll
            for (int mt = 0; mt < 4; ++mt) {
                const int r    = mt * 16 + (L & 15);
                const int kb16 = kc * 4 + (L >> 4);
                const int off  = r * 64 + ((kb16 ^ (r & 7)) << 3);
                ah[mt] = *reinterpret_cast<const bf16x8*>(&xh[off]);
                al[mt] = *reinterpret_cast<const bf16x8*>(&xl[off]);
            }
#pragma unroll
            for (int nt = 0; nt < 3; ++nt) {
                const size_t fidx =
                    ((size_t)((w * 3 + nt) * 32 + (ks * 2 + kc))) * 64 + L;
                const bf16x8 bh = *reinterpret_cast<const bf16x8*>(whf + fidx * 8);
                const bf16x8 bl = *reinterpret_cast<const bf16x8*>(wlf + fidx * 8);
#pragma unroll
                for (int mt = 0; mt < 4; ++mt) {
                    acc[mt][nt] = __builtin_amdgcn_mfma_f32_16x16x32_bf16(
                        ah[mt], bh, acc[mt][nt], 0, 0, 0);
                    acc[mt][nt] = __builtin_amdgcn_mfma_f32_16x16x32_bf16(
                        ah[mt], bl, acc[mt][nt], 0, 0, 0);
                    acc[mt][nt] = __builtin_amdgcn_mfma_f32_16x16x32_bf16(
                        al[mt], bh, acc[mt][nt], 0, 0, 0);
                }
            }
        }
    }

    // epilogue: C/D layout (m89-verified): col = L&15, row = (L>>4)*4 + reg
#pragma unroll
    for (int nt = 0; nt < 3; ++nt) {
        const int gc0 = w * 48 + nt * 16;            // multiple of 16
        float* dst = (gc0 < 64) ? q : (gc0 < 128) ? k : v;
        const int lc = (gc0 & 63) + (L & 15);
#pragma unroll
        for (int mt = 0; mt < 4; ++mt) {
#pragma unroll
            for (int reg = 0; reg < 4; ++reg) {
                const int grow = row0 + mt * 16 + (L >> 4) * 4 + reg;
                dst[(size_t)grow * HS + lc] = acc[mt][nt][reg];
            }
        }
    }
}

// ---------------------------------------------------------------------------
// Kernel 2: causal attention (unchanged from round 1; ~185 us).
// ---------------------------------------------------------------------------
__global__ __launch_bounds__(512) void attn_kernel(
    const float* __restrict__ q, const float* __restrict__ kmat,
    const float* __restrict__ vmat,
    float* __restrict__ A, float* __restrict__ out)
{
    __shared__ float s_lds[16 * TT];              // 128 KB score tile
    __shared__ float kv[64 * 68];                 // 17.4 KB k/v staging

    const int bid = blockIdx.x;
    const int b   = bid & 7;
    const int qt  = 127 - (bid >> 3);             // longest tiles first
    const int Q0  = qt * 16;

    const int tid = threadIdx.x;
    const int c   = tid & 31;
    const int r   = tid >> 5;
    const int grow = Q0 + r;
    const size_t base = (size_t)b * TT * HS;

    float4 qreg[16];
    {
        const float4* qrow =
            reinterpret_cast<const float4*>(q + base + (size_t)grow * HS);
#pragma unroll
        for (int i = 0; i < 16; ++i) qreg[i] = qrow[i];
    }

    const int ntiles = (Q0 + 15) / 64 + 1;

    // ---------------- Phase 1: QK^T ----------------
    for (int t = 0; t < ntiles; ++t) {
        __syncthreads();
        {
            const float4* src = reinterpret_cast<const float4*>(
                kmat + base + (size_t)t * 64 * HS);
#pragma unroll
            for (int i = 0; i < 2; ++i) {
                const int idx = tid + 512 * i;
                const int rw = idx >> 4, cc = idx & 15;
                *reinterpret_cast<float4*>(&kv[rw * 68 + cc * 4]) = src[idx];
            }
        }
        __syncthreads();
#pragma unroll
        for (int jj = 0; jj < 2; ++jj) {
            const int kr = c + 32 * jj;
            const int kg = t * 64 + kr;
            float acc = 0.f;
#pragma unroll
            for (int e4 = 0; e4 < 16; ++e4) {
                const float4 k4 =
                    *reinterpret_cast<const float4*>(&kv[kr * 68 + e4 * 4]);
                const float4 q4 = qreg[e4];
                acc += q4.x * k4.x + q4.y * k4.y + q4.z * k4.z + q4.w * k4.w;
            }
            if (kg > grow) acc = -1e30f;
            s_lds[r * TT + kg] = acc;
        }
    }
    for (int kg = ntiles * 64 + c; kg < TT; kg += 32)
        s_lds[r * TT + kg] = -1e30f;

    // ---------------- Phase 2: softmax ----------------
    float m = -1e30f;
#pragma unroll
    for (int j = 0; j < 64; ++j)
        m = fmaxf(m, s_lds[r * TT + c + 32 * j]);
#pragma unroll
    for (int mask = 16; mask > 0; mask >>= 1)
        m = fmaxf(m, __shfl_xor(m, mask, 32));

    float sum = 0.f;
#pragma unroll
    for (int j = 0; j < 64; ++j) {
        const int kg = c + 32 * j;
        const float e = __expf(s_lds[r * TT + kg] - m);
        s_lds[r * TT + kg] = e;
        sum += e;
    }
#pragma unroll
    for (int mask = 16; mask > 0; mask >>= 1)
        sum += __shfl_xor(sum, mask, 32);
    const float inv = 1.f / sum;

    float* Arow = A + ((size_t)b * TT + grow) * TT;
#pragma unroll
    for (int j = 0; j < 64; ++j) {
        const int kg = c + 32 * j;
        const float a = s_lds[r * TT + kg] * inv;
        s_lds[r * TT + kg] = a;
        Arow[kg] = a;
    }

    // ---------------- Phase 3: out = A @ v ----------------
    const int hh = tid & 63;
    const int rr = tid >> 6;
    float o1 = 0.f, o2 = 0.f;

    for (int t = 0; t < ntiles; ++t) {
        __syncthreads();
        {
            const float4* src = reinterpret_cast<const float4*>(
                vmat + base + (size_t)t * 64 * HS);
#pragma unroll
            for (int i = 0; i < 2; ++i) {
                const int idx = tid + 512 * i;
                const int rw = idx >> 4, cc = idx & 15;
                *reinterpret_cast<float4*>(&kv[rw * 68 + cc * 4]) = src[idx];
            }
        }
        __syncthreads();
#pragma unroll
        for (int kk4 = 0; kk4 < 16; ++kk4) {
            const float4 a1 = *reinterpret_cast<const float4*>(
                &s_lds[(size_t)rr * TT + t * 64 + kk4 * 4]);
            const float4 a2 = *reinterpret_cast<const float4*>(
                &s_lds[(size_t)(rr + 8) * TT + t * 64 + kk4 * 4]);
            const float* a1p = reinterpret_cast<const float*>(&a1);
            const float* a2p = reinterpret_cast<const float*>(&a2);
#pragma unroll
            for (int u = 0; u < 4; ++u) {
                const float vval = kv[(kk4 * 4 + u) * 68 + hh];
                o1 += a1p[u] * vval;
                o2 += a2p[u] * vval;
            }
        }
    }

    out[((size_t)b * TT + Q0 + rr) * HS + hh]     = o1;
    out[((size_t)b * TT + Q0 + rr + 8) * HS + hh] = o2;
}

// ---------------------------------------------------------------------------
extern "C" void kernel_launch(void* const* d_in, const int* in_sizes, int n_in,
                              void* d_out, int out_size, void* d_ws,
                              size_t ws_size, hipStream_t stream)
{
    (void)in_sizes; (void)n_in; (void)out_size; (void)ws_size;

    // setup_inputs() dict order: x, Wk, Wq, Wv
    const float* x  = (const float*)d_in[0];
    const float* Wk = (const float*)d_in[1];
    const float* Wq = (const float*)d_in[2];
    const float* Wv = (const float*)d_in[3];

    float* A   = (float*)d_out;                         // (B,T,T)
    float* out = A + (size_t)BB * TT * TT;              // (B,T,H)

    // workspace layout
    float* qd = (float*)d_ws;
    float* kd = qd + (size_t)BB * TT * HS;
    float* vd = kd + (size_t)BB * TT * HS;
    unsigned short* whf =
        (unsigned short*)((char*)d_ws + (size_t)12 * 1024 * 1024);
    unsigned short* wlf = whf + (size_t)24576 * 8;

    wprep_kernel<<<96, 256, 0, stream>>>(Wq, Wk, Wv, whf, wlf);
    proj_mfma<<<256, 256, 0, stream>>>(x, whf, wlf, qd, kd, vd);
    attn_kernel<<<BB * (TT / 16), 512, 0, stream>>>(qd, kd, vd, A, out);
}

// Round 3
// 114.691 us; speedup vs baseline: 5.6168x; 2.4652x over previous
//
#include <hip/hip_runtime.h>
#include <cstdint>
#include <cstddef>

#define NE 1024   // embedding dim
#define HS 64     // head size
#define TT 2048   // sequence length
#define BB 8      // batch

typedef short bf16x8 __attribute__((ext_vector_type(8)));
typedef float f32x4  __attribute__((ext_vector_type(4)));

// round-to-nearest-even f32 -> bf16 (bit pattern as ushort)
__device__ __forceinline__ unsigned short f2b(float f) {
    union { float f; uint32_t u; } v; v.f = f;
    uint32_t r = v.u + 0x7fffu + ((v.u >> 16) & 1u);
    return (unsigned short)(r >> 16);
}
__device__ __forceinline__ float b2f(unsigned short b) {
    union { uint32_t u; float f; } v; v.u = ((uint32_t)b) << 16;
    return v.f;
}

// ---------------------------------------------------------------------------
// Kernel 0: W = [Wq;Wk;Wv*0.125] (192x1024) -> MFMA B-fragments, split hi/lo.
// frag layout (16x16x32): lane L holds B[k=kcg*32+(L>>4)*8+j][col=ntg*16+(L&15)]
// ---------------------------------------------------------------------------
__global__ __launch_bounds__(256) void wprep_kernel(
    const float* __restrict__ Wq, const float* __restrict__ Wk,
    const float* __restrict__ Wv,
    unsigned short* __restrict__ whf, unsigned short* __restrict__ wlf)
{
    const int t   = blockIdx.x * 256 + threadIdx.x;   // 0..24575
    const int L   = t & 63;
    const int kcg = (t >> 6) & 31;
    const int ntg = t >> 11;                          // 0..11
    const int col = ntg * 16 + (L & 15);              // 0..191
    const int k0  = kcg * 32 + (L >> 4) * 8;

    const float* W;
    float scale = 1.f;
    if (col < 64)        W = Wq + (size_t)col * NE;
    else if (col < 128)  W = Wk + (size_t)(col - 64) * NE;
    else               { W = Wv + (size_t)(col - 128) * NE; scale = 0.125f; }

    bf16x8 h, l;
#pragma unroll
    for (int j = 0; j < 8; ++j) {
        const float f = W[k0 + j] * scale;
        const unsigned short hb = f2b(f);
        const unsigned short lb = f2b(f - b2f(hb));
        h[j] = (short)hb;
        l[j] = (short)lb;
    }
    *reinterpret_cast<bf16x8*>(whf + (size_t)t * 8) = h;
    *reinterpret_cast<bf16x8*>(wlf + (size_t)t * 8) = l;
}

// ---------------------------------------------------------------------------
// Kernel 1: projections via split-bf16 MFMA.
// Outputs: qh/ql, kh/kl row-major [B*T][64] bf16 (hi/lo split),
//          vT [B][64 h][T] bf16 (transposed, single precision, 0.125 folded).
// ---------------------------------------------------------------------------
__global__ __launch_bounds__(256) void proj_mfma(
    const float* __restrict__ x,
    const unsigned short* __restrict__ whf,
    const unsigned short* __restrict__ wlf,
    unsigned short* __restrict__ qh, unsigned short* __restrict__ ql,
    unsigned short* __restrict__ kh, unsigned short* __restrict__ kl,
    unsigned short* __restrict__ vT)
{
    __shared__ unsigned short xh[64 * 64];   // 8 KB, swizzled
    __shared__ unsigned short xl[64 * 64];   // 8 KB, swizzled

    const int tid  = threadIdx.x;
    const int L    = tid & 63;
    const int w    = tid >> 6;               // wave id 0..3
    const int row0 = blockIdx.x * 64;

    f32x4 acc[4][3];
#pragma unroll
    for (int mt = 0; mt < 4; ++mt)
#pragma unroll
        for (int nt = 0; nt < 3; ++nt)
#pragma unroll
            for (int r = 0; r < 4; ++r) acc[mt][nt][r] = 0.f;

    const int srow = tid >> 2;               // 0..63
    const int sk0  = (tid & 3) * 16;
    const float* xsrc = x + (size_t)(row0 + srow) * NE + sk0;

    for (int ks = 0; ks < 16; ++ks) {        // K loop, BK = 64
        __syncthreads();
        {
            const float4* s4 = reinterpret_cast<const float4*>(xsrc + ks * 64);
            float xv[16];
#pragma unroll
            for (int i = 0; i < 4; ++i) {
                const float4 f = s4[i];
                xv[4*i+0] = f.x; xv[4*i+1] = f.y; xv[4*i+2] = f.z; xv[4*i+3] = f.w;
            }
#pragma unroll
            for (int c = 0; c < 2; ++c) {
                bf16x8 hv, lv;
#pragma unroll
                for (int j = 0; j < 8; ++j) {
                    const float f = xv[c * 8 + j];
                    const unsigned short hb = f2b(f);
                    const unsigned short lb = f2b(f - b2f(hb));
                    hv[j] = (short)hb;
                    lv[j] = (short)lb;
                }
                const int kb16 = (tid & 3) * 2 + c;
                const int off  = srow * 64 + ((kb16 ^ (srow & 7)) << 3);
                *reinterpret_cast<bf16x8*>(&xh[off]) = hv;
                *reinterpret_cast<bf16x8*>(&xl[off]) = lv;
            }
        }
        __syncthreads();

#pragma unroll
        for (int kc = 0; kc < 2; ++kc) {
            bf16x8 ah[4], al[4];
#pragma unroll
            for (int mt = 0; mt < 4; ++mt) {
                const int r    = mt * 16 + (L & 15);
                const int kb16 = kc * 4 + (L >> 4);
                const int off  = r * 64 + ((kb16 ^ (r & 7)) << 3);
                ah[mt] = *reinterpret_cast<const bf16x8*>(&xh[off]);
                al[mt] = *reinterpret_cast<const bf16x8*>(&xl[off]);
            }
#pragma unroll
            for (int nt = 0; nt < 3; ++nt) {
                const size_t fidx =
                    ((size_t)((w * 3 + nt) * 32 + (ks * 2 + kc))) * 64 + L;
                const bf16x8 bh = *reinterpret_cast<const bf16x8*>(whf + fidx * 8);
                const bf16x8 bl = *reinterpret_cast<const bf16x8*>(wlf + fidx * 8);
#pragma unroll
                for (int mt = 0; mt < 4; ++mt) {
                    acc[mt][nt] = __builtin_amdgcn_mfma_f32_16x16x32_bf16(
                        ah[mt], bh, acc[mt][nt], 0, 0, 0);
                    acc[mt][nt] = __builtin_amdgcn_mfma_f32_16x16x32_bf16(
                        ah[mt], bl, acc[mt][nt], 0, 0, 0);
                    acc[mt][nt] = __builtin_amdgcn_mfma_f32_16x16x32_bf16(
                        al[mt], bh, acc[mt][nt], 0, 0, 0);
                }
            }
        }
    }

    // epilogue: C/D layout col=L&15, row=(L>>4)*4+reg
#pragma unroll
    for (int nt = 0; nt < 3; ++nt) {
        const int gc0 = w * 48 + nt * 16;
        const int lc  = L & 15;
#pragma unroll
        for (int mt = 0; mt < 4; ++mt) {
            const int t0g = row0 + mt * 16 + (L >> 4) * 4;   // row of reg 0
            if (gc0 < 128) {
                unsigned short* dh = (gc0 < 64) ? qh : kh;
                unsigned short* dl = (gc0 < 64) ? ql : kl;
                const int col = (gc0 & 63) + lc;
#pragma unroll
                for (int reg = 0; reg < 4; ++reg) {
                    const float val = acc[mt][nt][reg];
                    const unsigned short hb = f2b(val);
                    const unsigned short lb = f2b(val - b2f(hb));
                    dh[(size_t)(t0g + reg) * HS + col] = hb;
                    dl[(size_t)(t0g + reg) * HS + col] = lb;
                }
            } else {
                const int col  = (gc0 - 128) + lc;   // h index
                const int bat  = t0g >> 11;
                const int tloc = t0g & 2047;
                ushort4 pk;
                unsigned short* pp = reinterpret_cast<unsigned short*>(&pk);
#pragma unroll
                for (int reg = 0; reg < 4; ++reg)
                    pp[reg] = f2b(acc[mt][nt][reg]);
                *reinterpret_cast<ushort4*>(
                    &vT[((size_t)bat * HS + col) * TT + tloc]) = pk;
            }
        }
    }
}

// ---------------------------------------------------------------------------
// Kernel 2: MFMA causal attention. One block = 32 query rows of one batch.
// 512 threads = 8 waves. Wave w owns score col-tiles ct = w + 8i (16 cols
// each); scores live in acc[16][2] f32x4 registers. Softmax: 16-lane
// shfl_xor + LDS cross-wave reduce. A written f32 from regs; P (normalized,
// bf16) written to swizzled LDS; AV via MFMA with V^T B-frags from global.
// ---------------------------------------------------------------------------
__global__ __launch_bounds__(512, 2) void attn_mfma(
    const unsigned short* __restrict__ qh, const unsigned short* __restrict__ ql,
    const unsigned short* __restrict__ kh, const unsigned short* __restrict__ kl,
    const unsigned short* __restrict__ vT,
    float* __restrict__ A, float* __restrict__ out)
{
    __shared__ unsigned short P[32 * TT];    // 128 KB, 16B-chunk XOR swizzle
    __shared__ float redm[8][32];
    __shared__ float reds[8][32];
    __shared__ float mrow[32];
    __shared__ float sinv[32];

    const int tid = threadIdx.x;
    const int L   = tid & 63;
    const int w   = tid >> 6;                // wave 0..7
    const int b   = blockIdx.x & 7;          // batch == XCD slot
    const int qt  = 63 - (blockIdx.x >> 3);  // longest first
    const int Q0  = qt * 32;
    const int E   = Q0 + 32;                 // causal extent (mult of 32)
    const int g   = L >> 4;                  // lane quad 0..3
    const int l16 = L & 15;

    const size_t tbase = (size_t)b * TT;

    // ---- zero-fill A beyond causal extent (cols >= E) ----
    {
        const float4 z = {0.f, 0.f, 0.f, 0.f};
        const int r0  = tid >> 6;            // 0..7
        const int ct4 = tid & 63;
#pragma unroll
        for (int rr = 0; rr < 4; ++rr) {
            float4* dst = reinterpret_cast<float4*>(
                A + ((size_t)b * TT + Q0 + r0 + 8 * rr) * TT);
            for (int c4 = E / 4 + ct4; c4 < TT / 4; c4 += 64)
                dst[c4] = z;
        }
    }

    // ---- Q fragments (hi/lo), shared by all col-tiles of this wave ----
    bf16x8 qfh[2][2], qfl[2][2];             // [rowtile][kchunk]
#pragma unroll
    for (int rt = 0; rt < 2; ++rt)
#pragma unroll
        for (int kc = 0; kc < 2; ++kc) {
            const size_t off = (tbase + Q0 + rt * 16 + l16) * HS + kc * 32 + g * 8;
            qfh[rt][kc] = *reinterpret_cast<const bf16x8*>(qh + off);
            qfl[rt][kc] = *reinterpret_cast<const bf16x8*>(ql + off);
        }

    // ---- QK^T (split bf16: hh + hl + lh) ----
    f32x4 acc[16][2];
#pragma unroll
    for (int i = 0; i < 16; ++i)
#pragma unroll
        for (int rt = 0; rt < 2; ++rt)
#pragma unroll
            for (int r = 0; r < 4; ++r) acc[i][rt][r] = 0.f;

#pragma unroll
    for (int i = 0; i < 16; ++i) {
        const int k0 = (w + 8 * i) * 16;
        if (k0 < E) {
#pragma unroll
            for (int kc = 0; kc < 2; ++kc) {
                const size_t koff = (tbase + k0 + l16) * HS + kc * 32 + g * 8;
                const bf16x8 bh = *reinterpret_cast<const bf16x8*>(kh + koff);
                const bf16x8 bl = *reinterpret_cast<const bf16x8*>(kl + koff);
#pragma unroll
                for (int rt = 0; rt < 2; ++rt) {
                    acc[i][rt] = __builtin_amdgcn_mfma_f32_16x16x32_bf16(
                        qfh[rt][kc], bh, acc[i][rt], 0, 0, 0);
                    acc[i][rt] = __builtin_amdgcn_mfma_f32_16x16x32_bf16(
                        qfh[rt][kc], bl, acc[i][rt], 0, 0, 0);
                    acc[i][rt] = __builtin_amdgcn_mfma_f32_16x16x32_bf16(
                        qfl[rt][kc], bh, acc[i][rt], 0, 0, 0);
                }
            }
        }
    }

    // ---- causal mask + per-lane partial row max ----
    float pm[2][4];
#pragma unroll
    for (int rt = 0; rt < 2; ++rt)
#pragma unroll
        for (int r = 0; r < 4; ++r) pm[rt][r] = -3e38f;

#pragma unroll
    for (int i = 0; i < 16; ++i) {
        const int k0 = (w + 8 * i) * 16;
        if (k0 < E) {
            const int col = k0 + l16;
#pragma unroll
            for (int rt = 0; rt < 2; ++rt) {
                const int row = Q0 + rt * 16 + g * 4;
#pragma unroll
                for (int r = 0; r < 4; ++r) {
                    float s = acc[i][rt][r];
                    s = (col > row + r) ? -3e38f : s;
                    acc[i][rt][r] = s;
                    pm[rt][r] = fmaxf(pm[rt][r], s);
                }
            }
        }
    }
#pragma unroll
    for (int m = 1; m < 16; m <<= 1)
#pragma unroll
        for (int rt = 0; rt < 2; ++rt)
#pragma unroll
            for (int r = 0; r < 4; ++r)
                pm[rt][r] = fmaxf(pm[rt][r], __shfl_xor(pm[rt][r], m, 64));
    if (l16 == 0)
#pragma unroll
        for (int rt = 0; rt < 2; ++rt)
#pragma unroll
            for (int r = 0; r < 4; ++r)
                redm[w][rt * 16 + g * 4 + r] = pm[rt][r];
    __syncthreads();
    if (tid < 32) {
        float m = -3e38f;
#pragma unroll
        for (int ww = 0; ww < 8; ++ww) m = fmaxf(m, redm[ww][tid]);
        mrow[tid] = m;
    }
    __syncthreads();
    float mr[2][4];
#pragma unroll
    for (int rt = 0; rt < 2; ++rt)
#pragma unroll
        for (int r = 0; r < 4; ++r) mr[rt][r] = mrow[rt * 16 + g * 4 + r];

    // ---- exp (f32, in regs) + partial row sums ----
    float ps[2][4];
#pragma unroll
    for (int rt = 0; rt < 2; ++rt)
#pragma unroll
        for (int r = 0; r < 4; ++r) ps[rt][r] = 0.f;

#pragma unroll
    for (int i = 0; i < 16; ++i) {
        const int k0 = (w + 8 * i) * 16;
        if (k0 < E) {
#pragma unroll
            for (int rt = 0; rt < 2; ++rt)
#pragma unroll
                for (int r = 0; r < 4; ++r) {
                    const float e = __expf(acc[i][rt][r] - mr[rt][r]);
                    acc[i][rt][r] = e;
                    ps[rt][r] += e;
                }
        }
    }
#pragma unroll
    for (int m = 1; m < 16; m <<= 1)
#pragma unroll
        for (int rt = 0; rt < 2; ++rt)
#pragma unroll
            for (int r = 0; r < 4; ++r)
                ps[rt][r] += __shfl_xor(ps[rt][r], m, 64);
    if (l16 == 0)
#pragma unroll
        for (int rt = 0; rt < 2; ++rt)
#pragma unroll
            for (int r = 0; r < 4; ++r)
                reds[w][rt * 16 + g * 4 + r] = ps[rt][r];
    __syncthreads();
    if (tid < 32) {
        float s = 0.f;
#pragma unroll
        for (int ww = 0; ww < 8; ++ww) s += reds[ww][tid];
        sinv[tid] = 1.f / s;
    }
    __syncthreads();
    float iv[2][4];
#pragma unroll
    for (int rt = 0; rt < 2; ++rt)
#pragma unroll
        for (int r = 0; r < 4; ++r) iv[rt][r] = sinv[rt * 16 + g * 4 + r];

    // ---- write A (f32) + P (bf16, swizzled LDS) ----
#pragma unroll
    for (int i = 0; i < 16; ++i) {
        const int k0 = (w + 8 * i) * 16;
        if (k0 < E) {
            const int col   = k0 + l16;
            const int chunk = col >> 3;
            const int cl    = col & 7;
#pragma unroll
            for (int rt = 0; rt < 2; ++rt) {
                const int lrow = rt * 16 + g * 4;
#pragma unroll
                for (int r = 0; r < 4; ++r) {
                    const float a = acc[i][rt][r] * iv[rt][r];
                    A[((size_t)b * TT + Q0 + lrow + r) * TT + col] = a;
                    const int row = lrow + r;
                    P[row * 2048 + ((chunk ^ (row & 7)) << 3) + cl] = f2b(a);
                }
            }
        }
    }
    __syncthreads();

    // ---- out = P @ V via MFMA; wave w owns out tile (rt=w>>2, ht=w&3) ----
    const int rt_o = w >> 2;
    const int ht   = w & 3;
    f32x4 oacc;
#pragma unroll
    for (int r = 0; r < 4; ++r) oacc[r] = 0.f;

    const int nkk = E >> 5;
    const unsigned short* vbase = vT + ((size_t)b * HS + ht * 16 + l16) * TT;
    const int prow = rt_o * 16 + l16;
    for (int kk = 0; kk < nkk; ++kk) {
        const int chunk = kk * 4 + g;
        const bf16x8 pa = *reinterpret_cast<const bf16x8*>(
            &P[prow * 2048 + ((chunk ^ (prow & 7)) << 3)]);
        const bf16x8 vb = *reinterpret_cast<const bf16x8*>(vbase + kk * 32 + g * 8);
        oacc = __builtin_amdgcn_mfma_f32_16x16x32_bf16(pa, vb, oacc, 0, 0, 0);
    }
#pragma unroll
    for (int r = 0; r < 4; ++r)
        out[((size_t)b * TT + Q0 + rt_o * 16 + g * 4 + r) * HS + ht * 16 + l16] =
            oacc[r];
}

// ---------------------------------------------------------------------------
extern "C" void kernel_launch(void* const* d_in, const int* in_sizes, int n_in,
                              void* d_out, int out_size, void* d_ws,
                              size_t ws_size, hipStream_t stream)
{
    (void)in_sizes; (void)n_in; (void)out_size; (void)ws_size;

    // setup_inputs() dict order: x, Wk, Wq, Wv
    const float* x  = (const float*)d_in[0];
    const float* Wk = (const float*)d_in[1];
    const float* Wq = (const float*)d_in[2];
    const float* Wv = (const float*)d_in[3];

    float* A   = (float*)d_out;                         // (B,T,T)
    float* out = A + (size_t)BB * TT * TT;              // (B,T,H)

    // workspace: 5 bf16 arrays of B*T*H + W fragments  (10.75 MB total)
    const size_t NTH = (size_t)BB * TT * HS;            // 1048576
    unsigned short* qh  = (unsigned short*)d_ws;
    unsigned short* ql  = qh + NTH;
    unsigned short* kh  = ql + NTH;
    unsigned short* kl  = kh + NTH;
    unsigned short* vT  = kl + NTH;
    unsigned short* whf = vT + NTH;
    unsigned short* wlf = whf + (size_t)24576 * 8;

    wprep_kernel<<<96, 256, 0, stream>>>(Wq, Wk, Wv, whf, wlf);
    proj_mfma<<<256, 256, 0, stream>>>(x, whf, wlf, qh, ql, kh, kl, vT);
    attn_mfma<<<BB * (TT / 32), 512, 0, stream>>>(qh, ql, kh, kl, vT, A, out);
}